// Round 13
// baseline (498.253 us; speedup 1.0000x reference)
//
#include <hip/hip_runtime.h>
#include <hip/hip_bf16.h>

#define IN_CH 128
#define OUT_CH 256
#define BLK_SCAN 1024
#define AGG_STRIDE 132

typedef __bf16 bf16x8 __attribute__((ext_vector_type(8)));
typedef float f32x4 __attribute__((ext_vector_type(4)));
typedef float f32x2 __attribute__((ext_vector_type(2)));

__device__ inline unsigned short f2bf(float f) {
  union { float f; unsigned int u; } v; v.f = f;
  unsigned int u = v.u;
  u += 0x7FFFu + ((u >> 16) & 1u);   // round-to-nearest-even
  return (unsigned short)(u >> 16);
}
__device__ inline float bfhi2f(unsigned int u) {
  union { unsigned int u; float f; } v; v.u = u & 0xFFFF0000u; return v.f;
}
__device__ inline float bflo2f(unsigned int u) {
  union { unsigned int u; float f; } v; v.u = u << 16; return v.f;
}

// Bpack element layout (ushort): idx = (((tn*4+ks)*4+kb)*16 + c)*8 + j
//   value = bf16( W[tn*16+c][ks*32 + kb*8 + j] )   (same (kb,j)->k map as A frags)
__global__ void initB_kernel(const float* __restrict__ W, unsigned short* __restrict__ Bpack,
                             int* __restrict__ cnt, int nzero) {
  int i = blockIdx.x * blockDim.x + threadIdx.x;
  if (i < nzero) cnt[i] = 0;
  if (i < IN_CH * OUT_CH) {
    const int j  = i & 7;
    const int c  = (i >> 3) & 15;
    const int kb = (i >> 7) & 3;
    const int ks = (i >> 9) & 3;
    const int tn = i >> 11;
    Bpack[i] = f2bf(W[(size_t)(tn * 16 + c) * IN_CH + ks * 32 + kb * 8 + j]);
  }
}

// histogram into chunk-separated counters: cnt2[(e>=E2 ? N : 0) + col[e]]
__global__ void hist2_kernel(const int* __restrict__ col, int E, int E2,
                             int* __restrict__ cnt2, int N) {
  int i = blockIdx.x * blockDim.x + threadIdx.x;
  int b = i * 4;
  if (b + 4 <= E) {
    const int4 c = *(const int4*)(col + b);
    atomicAdd(&cnt2[((b + 0) >= E2 ? N : 0) + c.x], 1);
    atomicAdd(&cnt2[((b + 1) >= E2 ? N : 0) + c.y], 1);
    atomicAdd(&cnt2[((b + 2) >= E2 ? N : 0) + c.z], 1);
    atomicAdd(&cnt2[((b + 3) >= E2 ? N : 0) + c.w], 1);
  } else {
    for (int j = b; j < E; ++j) atomicAdd(&cnt2[(j >= E2 ? N : 0) + col[j]], 1);
  }
}

// ---------- scan kernels (length NN; in-place excl over count is safe) ----------
__global__ __launch_bounds__(BLK_SCAN) void scan_block_kernel(
    const int* __restrict__ count, int NN, int* __restrict__ excl, int* __restrict__ bsum) {
  __shared__ int wsum[16];
  const int tid = threadIdx.x;
  const int i = blockIdx.x * BLK_SCAN + tid;
  const int v = (i < NN) ? count[i] : 0;
  int x = v;
#pragma unroll
  for (int d = 1; d < 64; d <<= 1) {
    int t = __shfl_up(x, d, 64);
    if ((tid & 63) >= d) x += t;
  }
  if ((tid & 63) == 63) wsum[tid >> 6] = x;
  __syncthreads();
  if (tid < 16) {
    int s = wsum[tid];
#pragma unroll
    for (int d = 1; d < 16; d <<= 1) {
      int t = __shfl_up(s, d, 16);
      if (tid >= d) s += t;
    }
    wsum[tid] = s;
  }
  __syncthreads();
  const int w = tid >> 6;
  const int prefix = (w == 0) ? 0 : wsum[w - 1];
  if (i < NN) excl[i] = prefix + x - v;
  if (tid == BLK_SCAN - 1) bsum[blockIdx.x] = prefix + x;
}

__global__ void scan_bsum_kernel(int* __restrict__ bsum, int nb) {
  __shared__ int tmp[256];
  const int tid = threadIdx.x;
  int run = 0;
  for (int s = 0; s < nb; s += 256) {
    int v = (s + tid < nb) ? bsum[s + tid] : 0;
    tmp[tid] = v;
    __syncthreads();
    for (int d = 1; d < 256; d <<= 1) {
      int t = (tid >= d) ? tmp[tid - d] : 0;
      __syncthreads();
      tmp[tid] += t;
      __syncthreads();
    }
    if (s + tid < nb) bsum[s + tid] = run + tmp[tid] - v;
    run += tmp[255];
    __syncthreads();
  }
}

__global__ void add_offsets_kernel(int* __restrict__ excl, const int* __restrict__ bsum,
                                   int* __restrict__ cursor, int NN) {
  int i = blockIdx.x * blockDim.x + threadIdx.x;
  if (i < NN) {
    int o = excl[i] + bsum[i / BLK_SCAN];
    excl[i] = o;
    cursor[i] = o;
  }
}

// Stream te rows for edges [lo,hi) (NON-TEMPORAL reads: protect L3 for binned)
// -> write bf16 rows (256B) into per-node slots. cursor already chunk-offset.
__global__ __launch_bounds__(256) void bin_kernel(
    const float* __restrict__ te, const int* __restrict__ col,
    int* __restrict__ cursor, unsigned int* __restrict__ binned, int lo, int hi) {
  const int lane = threadIdx.x & 63;
  const int gw = (blockIdx.x * 256 + threadIdx.x) >> 6;
  const int nw = (gridDim.x * 256) >> 6;
  for (int base = lo + gw * 8; base < hi; base += nw * 8) {
    int ne = hi - base; if (ne > 8) ne = 8;
    int mypos = 0;
    if (lane < ne) {
      mypos = atomicAdd(&cursor[col[base + lane]], 1);
    }
#pragma unroll
    for (int j = 0; j < 8; ++j) {
      if (j < ne) {
        const int pos = __builtin_amdgcn_readlane(mypos, j);
        const f32x2 v = __builtin_nontemporal_load(
            (const f32x2*)(te + (size_t)(base + j) * IN_CH + lane * 2));
        binned[(size_t)pos * 64 + lane] =
            (unsigned int)f2bf(v[0]) | ((unsigned int)f2bf(v[1]) << 16);
      }
    }
  }
}

// Block = 16 nodes; wave owns 4 (serial q, batch-0 hoisted). Register
// accumulation; optionally adds the previous chunk's aggrow row (RAGG).
// !FINAL: write per-node bf16 row to aggrow.  FINAL: LDS + MFMA -> out.
// C/D layout: col=lane&15, row=(lane>>4)*4+reg  [HW-verified]
template <bool FINAL, bool RAGG>
__global__ __launch_bounds__(256) void phase2_kernel(
    const unsigned int* __restrict__ binned, const int* __restrict__ start,
    const int* __restrict__ cend, unsigned int* __restrict__ aggrow,
    const unsigned short* __restrict__ Bpack, const float* __restrict__ bias,
    float* __restrict__ out, int N) {
  __shared__ float agg[16][AGG_STRIDE];
  const int tid = threadIdx.x;
  const int wave = tid >> 6;
  const int lane = tid & 63;
  const int half = lane >> 5;
  const int li   = lane & 31;
  const int m0 = blockIdx.x * 16;

  int s0[4], e0[4];
  float acc[4][4];
  uint2 v[4][8];
#pragma unroll
  for (int q = 0; q < 4; ++q) {
    const int n = m0 + wave * 4 + q;
    s0[q] = (n < N) ? start[n] : 0;
    e0[q] = (n < N) ? cend[n] : 0;
#pragma unroll
    for (int c = 0; c < 4; ++c) acc[q][c] = 0.f;
  }
  // batch 0 for all 4 nodes: 32 uint2 loads in flight
#pragma unroll
  for (int q = 0; q < 4; ++q) {
#pragma unroll
    for (int j = 0; j < 8; ++j) {
      int row = s0[q] + 2 * j + half;
      row = (row < e0[q]) ? row : (e0[q] > s0[q] ? e0[q] - 1 : 0);
      v[q][j] = *(const uint2*)(binned + (size_t)row * 64 + li * 2);
    }
  }
#pragma unroll
  for (int q = 0; q < 4; ++q) {
    const int n = m0 + wave * 4 + q;
    const int rem = e0[q] - s0[q];
#pragma unroll
    for (int j = 0; j < 8; ++j) {
      const float c = (2 * j + half < rem) ? 1.f : 0.f;
      acc[q][0] = fmaf(c, bflo2f(v[q][j].x), acc[q][0]);
      acc[q][1] = fmaf(c, bfhi2f(v[q][j].x), acc[q][1]);
      acc[q][2] = fmaf(c, bflo2f(v[q][j].y), acc[q][2]);
      acc[q][3] = fmaf(c, bfhi2f(v[q][j].y), acc[q][3]);
    }
    for (int r0 = s0[q] + 16; r0 < e0[q]; r0 += 16) {
      const int rem2 = e0[q] - r0;
      uint2 w[8];
#pragma unroll
      for (int j = 0; j < 8; ++j) {
        int row = r0 + 2 * j + half;
        row = (row < e0[q]) ? row : (e0[q] - 1);
        w[j] = *(const uint2*)(binned + (size_t)row * 64 + li * 2);
      }
#pragma unroll
      for (int j = 0; j < 8; ++j) {
        const float c = (2 * j + half < rem2) ? 1.f : 0.f;
        acc[q][0] = fmaf(c, bflo2f(w[j].x), acc[q][0]);
        acc[q][1] = fmaf(c, bfhi2f(w[j].x), acc[q][1]);
        acc[q][2] = fmaf(c, bflo2f(w[j].y), acc[q][2]);
        acc[q][3] = fmaf(c, bfhi2f(w[j].y), acc[q][3]);
      }
    }
    if (RAGG) {  // add previous chunk's partial row (once per node: half 0)
      const int nn = (n < N) ? n : (N > 0 ? N - 1 : 0);
      const uint2 va = *(const uint2*)(aggrow + (size_t)nn * 64 + li * 2);
      const float c = (half == 0 && n < N) ? 1.f : 0.f;
      acc[q][0] = fmaf(c, bflo2f(va.x), acc[q][0]);
      acc[q][1] = fmaf(c, bfhi2f(va.x), acc[q][1]);
      acc[q][2] = fmaf(c, bflo2f(va.y), acc[q][2]);
      acc[q][3] = fmaf(c, bfhi2f(va.y), acc[q][3]);
    }
    acc[q][0] += __shfl_down(acc[q][0], 32);
    acc[q][1] += __shfl_down(acc[q][1], 32);
    acc[q][2] += __shfl_down(acc[q][2], 32);
    acc[q][3] += __shfl_down(acc[q][3], 32);
    if (half == 0) {
      if (FINAL) {
        *(float4*)(&agg[wave * 4 + q][4 * li]) =
            make_float4(acc[q][0], acc[q][1], acc[q][2], acc[q][3]);
      } else if (n < N) {
        uint2 o;
        o.x = (unsigned int)f2bf(acc[q][0]) | ((unsigned int)f2bf(acc[q][1]) << 16);
        o.y = (unsigned int)f2bf(acc[q][2]) | ((unsigned int)f2bf(acc[q][3]) << 16);
        *(uint2*)(aggrow + (size_t)n * 64 + li * 2) = o;
      }
    }
  }
  if (!FINAL) return;
  __syncthreads();

  // ---- fused MFMA projection for nodes [m0, m0+16) ----
  const int r  = lane & 15;
  const int kb = lane >> 4;

  bf16x8 a[4];
#pragma unroll
  for (int ks = 0; ks < 4; ++ks) {
    bf16x8 t;
#pragma unroll
    for (int j = 0; j < 8; ++j) t[j] = (__bf16)agg[r][ks * 32 + kb * 8 + j];
    a[ks] = t;
  }

  f32x4 accm[4];
#pragma unroll
  for (int ct = 0; ct < 4; ++ct) accm[ct] = (f32x4){0.f, 0.f, 0.f, 0.f};

#pragma unroll
  for (int ct = 0; ct < 4; ++ct) {
    const int tn = wave * 4 + ct;
#pragma unroll
    for (int ks = 0; ks < 4; ++ks) {
      const bf16x8 bb = *(const bf16x8*)(Bpack + (size_t)((((tn * 4 + ks) * 4 + kb) * 16 + r) * 8));
      accm[ct] = __builtin_amdgcn_mfma_f32_16x16x32_bf16(a[ks], bb, accm[ct], 0, 0, 0);
    }
  }

#pragma unroll
  for (int ct = 0; ct < 4; ++ct) {
    const int colo = wave * 64 + ct * 16 + r;
    const float bv = bias[colo];
#pragma unroll
    for (int j = 0; j < 4; ++j) {
      const int m = m0 + kb * 4 + j;
      if (m < N) __builtin_nontemporal_store(accm[ct][j] + bv, &out[(size_t)m * OUT_CH + colo]);
    }
  }
}

extern "C" void kernel_launch(void* const* d_in, const int* in_sizes, int n_in,
                              void* d_out, int out_size, void* d_ws, size_t ws_size,
                              hipStream_t stream) {
  const int* edge_index = (const int*)d_in[0];
  const float* te       = (const float*)d_in[1];
  const float* W        = (const float*)d_in[3];
  const float* bias     = (const float*)d_in[4];
  float* out            = (float*)d_out;

  const int E = in_sizes[0] / 2;
  const int N = out_size / OUT_CH;
  const int* col = edge_index + E;  // edge_index[1]

  const int NN = 2 * N;

  char* p = (char*)d_ws;
  unsigned short* Bpack = (unsigned short*)p;      p += 65536;
  int* cnt2   = (int*)p;                           p += (size_t)NN * 4;  // -> start2 in place
  int* cursor = (int*)p;                           p += (size_t)NN * 4;
  int* bsum   = (int*)p;                           p += 4096 * 4;
  p = (char*)(((uintptr_t)p + 255) & ~(uintptr_t)255);
  unsigned int* aggrow = (unsigned int*)p;         p += (size_t)N * 256;
  unsigned int* binned = (unsigned int*)p;         p += (size_t)E * 256;
  const size_t need2 = (size_t)(p - (char*)d_ws);

  const bool two_chunk = (ws_size >= need2);
  if (!two_chunk) binned = aggrow;  // single-chunk: reuse aggrow slot start for binned

  const int E2 = two_chunk ? (E / 2) : E;
  const int nb = (NN + BLK_SCAN - 1) / BLK_SCAN;
  const int init_n = (NN > IN_CH * OUT_CH) ? NN : IN_CH * OUT_CH;
  const int K = (N + 15) / 16;

  hipLaunchKernelGGL(initB_kernel, dim3((init_n + 255) / 256), dim3(256), 0, stream,
                     W, Bpack, cnt2, NN);
  hipLaunchKernelGGL(hist2_kernel, dim3((E / 4 + 255) / 256), dim3(256), 0, stream,
                     col, E, E2, cnt2, N);
  hipLaunchKernelGGL(scan_block_kernel, dim3(nb), dim3(BLK_SCAN), 0, stream,
                     cnt2, NN, cnt2, bsum);
  hipLaunchKernelGGL(scan_bsum_kernel, dim3(1), dim3(256), 0, stream, bsum, nb);
  hipLaunchKernelGGL(add_offsets_kernel, dim3((NN + 255) / 256), dim3(256), 0, stream,
                     cnt2, bsum, cursor, NN);

  // chunk A
  hipLaunchKernelGGL(bin_kernel, dim3(2048), dim3(256), 0, stream,
                     te, col, cursor, binned, 0, E2);
  if (two_chunk) {
    hipLaunchKernelGGL((phase2_kernel<false, false>), dim3(K), dim3(256), 0, stream,
                       binned, cnt2, cursor, aggrow, Bpack, bias, out, N);
    // chunk B
    hipLaunchKernelGGL(bin_kernel, dim3(2048), dim3(256), 0, stream,
                       te, col, cursor + N, binned, E2, E);
    hipLaunchKernelGGL((phase2_kernel<true, true>), dim3(K), dim3(256), 0, stream,
                       binned, cnt2 + N, cursor + N, aggrow, Bpack, bias, out, N);
  } else {
    hipLaunchKernelGGL((phase2_kernel<true, false>), dim3(K), dim3(256), 0, stream,
                       binned, cnt2, cursor, aggrow, Bpack, bias, out, N);
  }
}

// Round 14
// 438.735 us; speedup vs baseline: 1.1357x; 1.1357x over previous
//
#include <hip/hip_runtime.h>
#include <hip/hip_bf16.h>

#define IN_CH 128
#define OUT_CH 256
#define BLK_SCAN 1024

typedef __bf16 bf16x8 __attribute__((ext_vector_type(8)));
typedef float f32x4 __attribute__((ext_vector_type(4)));

__device__ inline unsigned short f2bf(float f) {
  union { float f; unsigned int u; } v; v.f = f;
  unsigned int u = v.u;
  u += 0x7FFFu + ((u >> 16) & 1u);   // round-to-nearest-even
  return (unsigned short)(u >> 16);
}

// fused init: zero count + build Bpack.
// Bpack element layout (ushort): idx = (((tn*4+ks)*4+kb)*16 + c)*8 + j
//   value = bf16( W[tn*16+c][ks*32 + kb*8 + j] )
__global__ void init_kernel(const float* __restrict__ W, unsigned short* __restrict__ Bpack,
                            int* __restrict__ count, int N) {
  int i = blockIdx.x * blockDim.x + threadIdx.x;
  if (i < N) count[i] = 0;
  if (i < IN_CH * OUT_CH) {
    const int j  = i & 7;
    const int c  = (i >> 3) & 15;
    const int kb = (i >> 7) & 3;
    const int ks = (i >> 9) & 3;
    const int tn = i >> 11;
    const int row = tn * 16 + c;
    const int k   = ks * 32 + kb * 8 + j;
    Bpack[i] = f2bf(W[(size_t)row * IN_CH + k]);
  }
}

// 4 edges per thread, int4 read of col
__global__ void hist_kernel(const int* __restrict__ col, int E, int* __restrict__ count) {
  int i = blockIdx.x * blockDim.x + threadIdx.x;
  int b = i * 4;
  if (b + 4 <= E) {
    const int4 c = *(const int4*)(col + b);
    atomicAdd(&count[c.x], 1);
    atomicAdd(&count[c.y], 1);
    atomicAdd(&count[c.z], 1);
    atomicAdd(&count[c.w], 1);
  } else {
    for (int j = b; j < E; ++j) atomicAdd(&count[col[j]], 1);
  }
}

// shfl-based block scan: 3 barriers
__global__ __launch_bounds__(BLK_SCAN) void scan_block_kernel(
    const int* __restrict__ count, int N, int* __restrict__ excl, int* __restrict__ bsum) {
  __shared__ int wsum[16];
  const int tid = threadIdx.x;
  const int i = blockIdx.x * BLK_SCAN + tid;
  const int v = (i < N) ? count[i] : 0;
  int x = v;
#pragma unroll
  for (int d = 1; d < 64; d <<= 1) {
    int t = __shfl_up(x, d, 64);
    if ((tid & 63) >= d) x += t;
  }
  if ((tid & 63) == 63) wsum[tid >> 6] = x;
  __syncthreads();
  if (tid < 16) {
    int s = wsum[tid];
#pragma unroll
    for (int d = 1; d < 16; d <<= 1) {
      int t = __shfl_up(s, d, 16);
      if (tid >= d) s += t;
    }
    wsum[tid] = s;
  }
  __syncthreads();
  const int w = tid >> 6;
  const int prefix = (w == 0) ? 0 : wsum[w - 1];
  if (i < N) excl[i] = prefix + x - v;
  if (tid == BLK_SCAN - 1) bsum[blockIdx.x] = prefix + x;
}

__global__ void scan_bsum_kernel(int* __restrict__ bsum, int nb) {
  __shared__ int tmp[256];
  const int tid = threadIdx.x;
  int run = 0;
  for (int s = 0; s < nb; s += 256) {
    int v = (s + tid < nb) ? bsum[s + tid] : 0;
    tmp[tid] = v;
    __syncthreads();
    for (int d = 1; d < 256; d <<= 1) {
      int t = (tid >= d) ? tmp[tid - d] : 0;
      __syncthreads();
      tmp[tid] += t;
      __syncthreads();
    }
    if (s + tid < nb) bsum[s + tid] = run + tmp[tid] - v;
    run += tmp[255];
    __syncthreads();
  }
}

__global__ void add_offsets_kernel(int* __restrict__ excl, const int* __restrict__ bsum,
                                   int* __restrict__ cursor, int N) {
  int i = blockIdx.x * blockDim.x + threadIdx.x;
  if (i < N) {
    int o = excl[i] + bsum[i / BLK_SCAN];
    excl[i] = o;
    cursor[i] = o;
  }
}

// 4 edges per thread, int4 read of col
__global__ void scatter_kernel(const int* __restrict__ col, int E,
                               int* __restrict__ cursor, int* __restrict__ sorted) {
  int i = blockIdx.x * blockDim.x + threadIdx.x;
  int b = i * 4;
  if (b + 4 <= E) {
    const int4 c = *(const int4*)(col + b);
    int p0 = atomicAdd(&cursor[c.x], 1); sorted[p0] = b;
    int p1 = atomicAdd(&cursor[c.y], 1); sorted[p1] = b + 1;
    int p2 = atomicAdd(&cursor[c.z], 1); sorted[p2] = b + 2;
    int p3 = atomicAdd(&cursor[c.w], 1); sorted[p3] = b + 3;
  } else {
    for (int j = b; j < E; ++j) {
      int pos = atomicAdd(&cursor[col[j]], 1);
      sorted[pos] = j;
    }
  }
}

// One node per wave; 16 rows in flight per iteration.
// eids broadcast via READLANE -> SGPR base addressing (SALU, not per-lane v_mad_u64).
__global__ __launch_bounds__(256) void aggregate_kernel(
    const float* __restrict__ te, const int* __restrict__ offsets,
    const int* __restrict__ cend, const int* __restrict__ sorted,
    unsigned int* __restrict__ aggb32, int N) {
  const int g    = threadIdx.x >> 6;
  const int lane = threadIdx.x & 63;
  const int n = blockIdx.x * 4 + g;
  if (n >= N) return;

  float ax = 0.f, ay = 0.f;
  const int s = offsets[n];
  const int e = cend[n];
  const size_t co = (size_t)(lane * 2);
  if (s < e) {
    int my = 0;
    if (lane < 16) {
      int idx = s + lane;
      my = sorted[idx < e ? idx : (e - 1)];
    }
    for (int i = s; i < e; i += 16) {
#define EID(j) __builtin_amdgcn_readlane(my, j)
      const float2 t0  = *(const float2*)(te + (size_t)EID(0)  * IN_CH + co);
      const float2 t1  = *(const float2*)(te + (size_t)EID(1)  * IN_CH + co);
      const float2 t2  = *(const float2*)(te + (size_t)EID(2)  * IN_CH + co);
      const float2 t3  = *(const float2*)(te + (size_t)EID(3)  * IN_CH + co);
      const float2 t4  = *(const float2*)(te + (size_t)EID(4)  * IN_CH + co);
      const float2 t5  = *(const float2*)(te + (size_t)EID(5)  * IN_CH + co);
      const float2 t6  = *(const float2*)(te + (size_t)EID(6)  * IN_CH + co);
      const float2 t7  = *(const float2*)(te + (size_t)EID(7)  * IN_CH + co);
      const float2 t8  = *(const float2*)(te + (size_t)EID(8)  * IN_CH + co);
      const float2 t9  = *(const float2*)(te + (size_t)EID(9)  * IN_CH + co);
      const float2 t10 = *(const float2*)(te + (size_t)EID(10) * IN_CH + co);
      const float2 t11 = *(const float2*)(te + (size_t)EID(11) * IN_CH + co);
      const float2 t12 = *(const float2*)(te + (size_t)EID(12) * IN_CH + co);
      const float2 t13 = *(const float2*)(te + (size_t)EID(13) * IN_CH + co);
      const float2 t14 = *(const float2*)(te + (size_t)EID(14) * IN_CH + co);
      const float2 t15 = *(const float2*)(te + (size_t)EID(15) * IN_CH + co);
#undef EID
      // prefetch next sorted batch while row loads are in flight
      int nxt = 0;
      {
        const int ib = i + 16;
        if (lane < 16 && ib < e) {
          int idx = ib + lane;
          nxt = sorted[idx < e ? idx : (e - 1)];
        }
      }
      const int rem = e - i;  // wave-uniform
      if (rem >= 16) {
        ax += (t0.x + t1.x) + (t2.x + t3.x) + (t4.x + t5.x) + (t6.x + t7.x) +
              (t8.x + t9.x) + (t10.x + t11.x) + (t12.x + t13.x) + (t14.x + t15.x);
        ay += (t0.y + t1.y) + (t2.y + t3.y) + (t4.y + t5.y) + (t6.y + t7.y) +
              (t8.y + t9.y) + (t10.y + t11.y) + (t12.y + t13.y) + (t14.y + t15.y);
      } else {
        ax += t0.x; ay += t0.y;
#define ACC(j, tj) { const float c = (rem > j) ? 1.f : 0.f; \
                     ax = fmaf(c, tj.x, ax); ay = fmaf(c, tj.y, ay); }
        ACC(1, t1)  ACC(2, t2)  ACC(3, t3)  ACC(4, t4)  ACC(5, t5)
        ACC(6, t6)  ACC(7, t7)  ACC(8, t8)  ACC(9, t9)  ACC(10, t10)
        ACC(11, t11) ACC(12, t12) ACC(13, t13) ACC(14, t14) ACC(15, t15)
#undef ACC
      }
      my = nxt;
    }
  }
  aggb32[(size_t)n * 64 + lane] = (unsigned int)f2bf(ax) | ((unsigned int)f2bf(ay) << 16);
}

// MFMA projection: C[N,256] = aggb[N,128] @ W^T + b.
__global__ __launch_bounds__(256) void project_mfma(
    const unsigned short* __restrict__ aggb, const unsigned short* __restrict__ Bpack,
    const float* __restrict__ bias, float* __restrict__ out, int N) {
  const int wave = threadIdx.x >> 6;
  const int lane = threadIdx.x & 63;
  const int r  = lane & 15;
  const int kb = lane >> 4;
  const int m0 = blockIdx.x * 16;

  bf16x8 a[4];
  const unsigned short* arow = aggb + (size_t)(m0 + r) * IN_CH + kb * 8;
#pragma unroll
  for (int ks = 0; ks < 4; ++ks)
    a[ks] = *(const bf16x8*)(arow + ks * 32);

  f32x4 acc[4];
#pragma unroll
  for (int ct = 0; ct < 4; ++ct) acc[ct] = (f32x4){0.f, 0.f, 0.f, 0.f};

#pragma unroll
  for (int ct = 0; ct < 4; ++ct) {
    const int tn = wave * 4 + ct;
#pragma unroll
    for (int ks = 0; ks < 4; ++ks) {
      const bf16x8 b = *(const bf16x8*)(Bpack + (size_t)((((tn * 4 + ks) * 4 + kb) * 16 + r) * 8));
      acc[ct] = __builtin_amdgcn_mfma_f32_16x16x32_bf16(a[ks], b, acc[ct], 0, 0, 0);
    }
  }

#pragma unroll
  for (int ct = 0; ct < 4; ++ct) {
    const int col = wave * 64 + ct * 16 + r;
    const float bv = bias[col];
#pragma unroll
    for (int j = 0; j < 4; ++j) {
      const int m = m0 + kb * 4 + j;
      if (m < N) out[(size_t)m * OUT_CH + col] = acc[ct][j] + bv;
    }
  }
}

extern "C" void kernel_launch(void* const* d_in, const int* in_sizes, int n_in,
                              void* d_out, int out_size, void* d_ws, size_t ws_size,
                              hipStream_t stream) {
  const int* edge_index = (const int*)d_in[0];
  const float* te       = (const float*)d_in[1];
  const float* W        = (const float*)d_in[3];
  const float* bias     = (const float*)d_in[4];
  float* out            = (float*)d_out;

  const int E = in_sizes[0] / 2;
  const int N = out_size / OUT_CH;
  const int* col = edge_index + E;

  const int Np = (N + 3) & ~3;
  const int Ep = (E + 3) & ~3;
  int* ws      = (int*)d_ws;
  int* count   = ws;                          // Np
  int* offsets = ws + Np;                     // Np
  int* cursor  = ws + 2 * Np;                 // Np
  int* bsum    = ws + 3 * Np;                 // 4096
  int* sorted  = ws + 3 * Np + 4096;          // Ep
  unsigned short* Bpack = (unsigned short*)(ws + 3 * Np + 4096 + Ep);        // 32768 ushort
  unsigned int*   aggb  = (unsigned int*)(ws + 3 * Np + 4096 + Ep + 16384);  // N*64 uint

  const int nb = (N + BLK_SCAN - 1) / BLK_SCAN;
  const int init_n = (N > IN_CH * OUT_CH) ? N : IN_CH * OUT_CH;

  hipLaunchKernelGGL(init_kernel, dim3((init_n + 255) / 256), dim3(256), 0, stream,
                     W, Bpack, count, N);
  hipLaunchKernelGGL(hist_kernel, dim3((E / 4 + 255) / 256), dim3(256), 0, stream, col, E, count);
  hipLaunchKernelGGL(scan_block_kernel, dim3(nb), dim3(BLK_SCAN), 0, stream, count, N, offsets, bsum);
  hipLaunchKernelGGL(scan_bsum_kernel, dim3(1), dim3(256), 0, stream, bsum, nb);
  hipLaunchKernelGGL(add_offsets_kernel, dim3((N + 255) / 256), dim3(256), 0, stream,
                     offsets, bsum, cursor, N);
  hipLaunchKernelGGL(scatter_kernel, dim3((E / 4 + 255) / 256), dim3(256), 0, stream,
                     col, E, cursor, sorted);
  hipLaunchKernelGGL(aggregate_kernel, dim3((N + 3) / 4), dim3(256), 0, stream,
                     te, offsets, cursor, sorted, aggb, N);
  hipLaunchKernelGGL(project_mfma, dim3((N + 15) / 16), dim3(256), 0, stream,
                     (const unsigned short*)aggb, Bpack, bias, out, N);
}